// Round 11
// baseline (166.414 us; speedup 1.0000x reference)
//
#include <hip/hip_runtime.h>

// RegionAttention: bf16 MFMA everywhere; attention uses MFMA for QK, EPEG-conv
// (banded matmul), and PV; no-max softmax in exp2 domain; deferred row-sum.
// R11 = R10 + P aliases the retired K/V LDS buffers (LDS 67.5->52.3 KB ->
// 3 blocks/CU, occupancy +50%) + s_setprio(1) around MFMA clusters.
// q is PRE-SCALED by 0.125*log2(e).

using bf16x8 = __attribute__((ext_vector_type(8))) short;
using f32x4  = __attribute__((ext_vector_type(4))) float;

__device__ __forceinline__ unsigned short f2bf(float f) {
    unsigned u = __float_as_uint(f);
    u += 0x7fff + ((u >> 16) & 1);
    return (unsigned short)(u >> 16);
}
__device__ __forceinline__ unsigned cvtpk(float lo, float hi) {
    unsigned r;
    asm("v_cvt_pk_bf16_f32 %0, %1, %2" : "=v"(r) : "v"(lo), "v"(hi));
    return r;
}
__device__ __forceinline__ void gload16(const void* g, void* l) {
    __builtin_amdgcn_global_load_lds(
        (const __attribute__((address_space(1))) void*)g,
        (__attribute__((address_space(3))) void*)l, 16, 0, 0);
}
__device__ __forceinline__ int l_from_rn(int region, int n) {
    int gi = region >> 2, gj = region & 3;
    int a = n >> 5, b = n & 31;
    return ((gi * 32 + a) << 7) + (gj << 5) + b;
}

// ---------------- cast kernels ----------------
__global__ __launch_bounds__(256) void cast_x_kernel(
    const float* __restrict__ x, unsigned short* __restrict__ xb)
{
    int tid = threadIdx.x;
    int t = blockIdx.x * 4 + (tid >> 6);
    int c8 = tid & 63;
    int l = l_from_rn(t >> 10, t & 1023);
    const float* src = x + (size_t)l * 512 + c8 * 8;
    float4 a = *(const float4*)src;
    float4 b = *(const float4*)(src + 4);
    bf16x8 o;
    o[0] = (short)f2bf(a.x); o[1] = (short)f2bf(a.y);
    o[2] = (short)f2bf(a.z); o[3] = (short)f2bf(a.w);
    o[4] = (short)f2bf(b.x); o[5] = (short)f2bf(b.y);
    o[6] = (short)f2bf(b.z); o[7] = (short)f2bf(b.w);
    *(bf16x8*)(xb + (size_t)t * 512 + c8 * 8) = o;
}

__global__ __launch_bounds__(256) void cast_w_kernel(
    const float* __restrict__ w, unsigned short* __restrict__ wb)
{
    int g = blockIdx.x * 256 + threadIdx.x;
    const float* src = w + (size_t)g * 8;
    float4 a = *(const float4*)src;
    float4 b = *(const float4*)(src + 4);
    bf16x8 o;
    o[0] = (short)f2bf(a.x); o[1] = (short)f2bf(a.y);
    o[2] = (short)f2bf(a.z); o[3] = (short)f2bf(a.w);
    o[4] = (short)f2bf(b.x); o[5] = (short)f2bf(b.y);
    o[6] = (short)f2bf(b.z); o[7] = (short)f2bf(b.w);
    *(bf16x8*)(wb + (size_t)g * 8) = o;
}

// ---------------- Kernel 1: QKV GEMM (bf16 MFMA) ----------------
__global__ __launch_bounds__(256) void qkv_kernel(
    const unsigned short* __restrict__ xb, const unsigned short* __restrict__ wb,
    const float* __restrict__ bias, unsigned short* __restrict__ qo,
    unsigned short* __restrict__ ko, unsigned short* __restrict__ vto)
{
    __shared__ __align__(16) unsigned short As[128 * 64];
    __shared__ __align__(16) unsigned short Bs[128 * 64];
    const int c0t = blockIdx.x * 128;
    const int t0 = blockIdx.y * 128;
    const int tid = threadIdx.x;
    const int lane = tid & 63, w = tid >> 6;
    const int arow = lane & 15, kgrp = lane >> 4;
    const int wr = w >> 1, wc = w & 1;

    f32x4 acc[4][4];
    #pragma unroll
    for (int m = 0; m < 4; ++m)
        #pragma unroll
        for (int n = 0; n < 4; ++n) {
            f32x4 z = {0.f, 0.f, 0.f, 0.f};
            acc[m][n] = z;
        }

    for (int k0 = 0; k0 < 512; k0 += 64) {
        __syncthreads();
        #pragma unroll
        for (int it = 0; it < 4; ++it) {
            int slot = it * 256 + tid;
            int row = slot >> 3, phys = slot & 7;
            int c8 = phys ^ (row & 7);
            gload16(xb + (size_t)(t0 + row) * 512 + k0 + c8 * 8,
                    &As[(it * 256 + (w << 6)) * 8]);
            gload16(wb + (size_t)(c0t + row) * 512 + k0 + c8 * 8,
                    &Bs[(it * 256 + (w << 6)) * 8]);
        }
        __syncthreads();

        bf16x8 af[4][2], bfr[4][2];
        #pragma unroll
        for (int m = 0; m < 4; ++m) {
            int r = wr * 64 + m * 16 + arow;
            af[m][0] = *(const bf16x8*)&As[r * 64 + ((kgrp ^ (r & 7)) * 8)];
            af[m][1] = *(const bf16x8*)&As[r * 64 + (((4 + kgrp) ^ (r & 7)) * 8)];
        }
        #pragma unroll
        for (int n = 0; n < 4; ++n) {
            int r = wc * 64 + n * 16 + arow;
            bfr[n][0] = *(const bf16x8*)&Bs[r * 64 + ((kgrp ^ (r & 7)) * 8)];
            bfr[n][1] = *(const bf16x8*)&Bs[r * 64 + (((4 + kgrp) ^ (r & 7)) * 8)];
        }
        #pragma unroll
        for (int m = 0; m < 4; ++m)
            #pragma unroll
            for (int n = 0; n < 4; ++n) {
                acc[m][n] = __builtin_amdgcn_mfma_f32_16x16x32_bf16(
                    af[m][0], bfr[n][0], acc[m][n], 0, 0, 0);
                acc[m][n] = __builtin_amdgcn_mfma_f32_16x16x32_bf16(
                    af[m][1], bfr[n][1], acc[m][n], 0, 0, 0);
            }
    }

    const int s = c0t >> 9;
    const int region = t0 >> 10;
    // q pre-scale: 0.125 (attn scale) * log2(e) (exp2-domain softmax)
    const float qs = (s == 0) ? 0.18033688f : 1.0f;
    #pragma unroll
    for (int n = 0; n < 4; ++n) {
        int cg = c0t + wc * 64 + n * 16 + arow;
        float bi = bias[cg];
        int h = (cg >> 6) & 7, d = cg & 63;
        if (s < 2) {
            unsigned short* dst = (s == 0) ? qo : ko;
            #pragma unroll
            for (int m = 0; m < 4; ++m) {
                int tb = t0 + wr * 64 + m * 16 + kgrp * 4;
                unsigned short* p =
                    dst + ((size_t)(region * 8 + h) * 1024 + (tb & 1023)) * 64 + d;
                #pragma unroll
                for (int i = 0; i < 4; ++i)
                    p[(size_t)i * 64] = f2bf((acc[m][n][i] + bi) * qs);
            }
        } else {
            #pragma unroll
            for (int m = 0; m < 4; ++m) {
                int tb = t0 + wr * 64 + m * 16 + kgrp * 4;
                ushort4 pk;
                pk.x = f2bf(acc[m][n][0] + bi);
                pk.y = f2bf(acc[m][n][1] + bi);
                pk.z = f2bf(acc[m][n][2] + bi);
                pk.w = f2bf(acc[m][n][3] + bi);
                *(ushort4*)(vto + (size_t)(region * 8 + h) * 65536 +
                            (size_t)d * 1024 + (tb & 1023)) = pk;
            }
        }
    }
}

// ---------------- Kernel 2: all-MFMA attention, QBLK=128, q-split waves -----------
__global__ __launch_bounds__(256) void attn_kernel(
    const unsigned short* __restrict__ qg, const unsigned short* __restrict__ kg,
    const unsigned short* __restrict__ vtg, const float* __restrict__ epw,
    const float* __restrict__ epb, unsigned short* __restrict__ ao)
{
    // XCD swizzle: 1024 blocks; all 8 i-blocks of one rh on one XCD
    const int bid = blockIdx.x;
    const int wid = (bid & 7) * 128 + (bid >> 3);
    const int rb = wid & 7;          // i-block (128 q rows)
    const int rh = wid >> 3;         // region*8 + head
    const int head = rh & 7, region = rh >> 3;
    const unsigned short* qb = qg + (size_t)rh * 65536;
    const unsigned short* kb = kg + (size_t)rh * 65536;
    const unsigned short* vb = vtg + (size_t)rh * 65536;
    const int i0 = rb * 128;
    const int tid = threadIdx.x;
    const int lane = tid & 63, w = tid >> 6;
    const int arow = lane & 15, kgrp = lane >> 4;

    __shared__ __align__(16) unsigned short Ks[2][4096];
    __shared__ __align__(16) unsigned short VTs[2][4096];
    __shared__ __align__(16) unsigned char ST2[64 * 304]; // S^T [j][q], 304B rows
    __shared__ float row_l[128];
    // P (128 q rows x 128 B) aliases the RETIRED K/V buffers after mid barrier:
    // rows 0..63 -> Ks[cur], rows 64..127 -> VTs[cur].

    char* const st2b = (char*)ST2;
    // zero ST2 pad regions per row: bytes 0..3 (q=-4,-3) and 268..303 (q>=130)
    for (int idx = tid; idx < 640; idx += 256) {
        int j = idx / 10, sl = idx % 10;
        int off = (sl == 0) ? 0 : (264 + sl * 4);
        *(unsigned*)(st2b + j * 304 + off) = 0u;
    }

    // Q fragments: wave owns q in [w*32, w*32+32), two 16-row groups
    bf16x8 qf[2][2];
    #pragma unroll
    for (int m = 0; m < 2; ++m) {
        const unsigned short* p =
            qb + (size_t)(i0 + w * 32 + m * 16 + arow) * 64 + kgrp * 8;
        qf[m][0] = *(const bf16x8*)p;
        qf[m][1] = *(const bf16x8*)(p + 32);
    }
    // halo Q fragment: A-rows 0..3 = q rows {i0-2,i0-1,i0+128,i0+129}, rest zero
    bf16x8 qhf0, qhf1;
    #pragma unroll
    for (int e = 0; e < 8; ++e) { qhf0[e] = 0; qhf1[e] = 0; }
    {
        int gi = (arow < 2) ? (i0 - 2 + arow) : (i0 + 126 + arow);
        if (arow < 4 && gi >= 0 && gi < 1024) {
            const unsigned short* p = qb + (size_t)gi * 64 + kgrp * 8;
            qhf0 = *(const bf16x8*)p;
            qhf1 = *(const bf16x8*)(p + 32);
        }
    }

    // Band B-fragment (constant): B[k][n=arow] = cwt[k-n-2], k = kgrp*8+e
    bf16x8 bandf;
    {
        float cwt[5];
        #pragma unroll
        for (int t = 0; t < 5; ++t) cwt[t] = epw[head * 5 + t];
        cwt[2] += 1.0f;   // identity (direct S) term
        #pragma unroll
        for (int e = 0; e < 8; ++e) {
            int c = kgrp * 8 + e - arow - 2;
            float v = 0.f;
            v = (c == 0) ? cwt[0] : v;
            v = (c == 1) ? cwt[1] : v;
            v = (c == 2) ? cwt[2] : v;
            v = (c == 3) ? cwt[3] : v;
            v = (c == 4) ? cwt[4] : v;
            bandf[e] = (short)f2bf(v);
        }
    }

    f32x4 oacc[2][4];
    #pragma unroll
    for (int m = 0; m < 2; ++m)
        #pragma unroll
        for (int dt = 0; dt < 4; ++dt) {
            f32x4 z = {0.f, 0.f, 0.f, 0.f};
            oacc[m][dt] = z;
        }
    float lp[2] = {0.f, 0.f};

    auto stage = [&](int jt, int buf) {
        const int j0 = jt * 64;
        #pragma unroll
        for (int it = 0; it < 2; ++it) {
            int q_ = (it * 4 + w) * 64 + lane;
            int row = q_ >> 3, phys = q_ & 7, c8 = phys ^ (row & 7);
            gload16(kb + (size_t)(j0 + row) * 64 + c8 * 8,
                    &Ks[buf][(it * 4 + w) * 512]);
            gload16(vb + (size_t)row * 1024 + j0 + c8 * 8,
                    &VTs[buf][(it * 4 + w) * 512]);
        }
    };

    stage(0, 0);

    for (int jt = 0; jt < 16; ++jt) {
        const int cur = jt & 1;
        __syncthreads();   // staged tile landed; P/ST2 reads of prev tile done
        if (jt < 15) stage(jt + 1, cur ^ 1);

        const unsigned short* Kc = &Ks[cur][0];
        const unsigned short* Vc = &VTs[cur][0];
        // P base for this tile (aliases retired buffers, valid post mid-barrier)
        char* const pbase = (w < 2) ? (char*)&Ks[cur][0] : (char*)&VTs[cur][0];
        const int plrow0 = (w & 1) * 32 + arow;   // + m*16 per group

        // hoisted V fragments (valid post-barrier; overlap QK/S^T phase)
        bf16x8 vf[4][2];
        #pragma unroll
        for (int dt = 0; dt < 4; ++dt) {
            int drow = dt * 16 + arow;
            vf[dt][0] = *(const bf16x8*)&Vc[drow * 64 + ((kgrp ^ (drow & 7)) * 8)];
            vf[dt][1] = *(const bf16x8*)&Vc[drow * 64 + (((4 + kgrp) ^ (drow & 7)) * 8)];
        }

        // QK -> S^T bf16: wave w writes q cols [w*32, w*32+32) of all 64 j rows
        __builtin_amdgcn_s_setprio(1);
        #pragma unroll
        for (int ct = 0; ct < 4; ++ct) {
            int krow = ct * 16 + arow;
            bf16x8 kf0 = *(const bf16x8*)&Kc[krow * 64 + ((kgrp ^ (krow & 7)) * 8)];
            bf16x8 kf1 = *(const bf16x8*)&Kc[krow * 64 + (((4 + kgrp) ^ (krow & 7)) * 8)];
            char* const srow = st2b + krow * 304;
            #pragma unroll
            for (int m = 0; m < 2; ++m) {
                f32x4 sacc = {0.f, 0.f, 0.f, 0.f};
                sacc = __builtin_amdgcn_mfma_f32_16x16x32_bf16(qf[m][0], kf0, sacc, 0, 0, 0);
                sacc = __builtin_amdgcn_mfma_f32_16x16x32_bf16(qf[m][1], kf1, sacc, 0, 0, 0);
                uint2 uu;
                uu.x = cvtpk(sacc[0], sacc[1]);
                uu.y = cvtpk(sacc[2], sacc[3]);
                *(uint2*)(srow + 8 + w * 64 + m * 32 + kgrp * 8) = uu;
            }
            if (ct == w) {   // halo rows for this wave's 16-j group
                f32x4 hacc = {0.f, 0.f, 0.f, 0.f};
                hacc = __builtin_amdgcn_mfma_f32_16x16x32_bf16(qhf0, kf0, hacc, 0, 0, 0);
                hacc = __builtin_amdgcn_mfma_f32_16x16x32_bf16(qhf1, kf1, hacc, 0, 0, 0);
                if (kgrp == 0) {
                    *(unsigned*)(srow + 4)   = cvtpk(hacc[0], hacc[1]);   // q=-2,-1
                    *(unsigned*)(srow + 264) = cvtpk(hacc[2], hacc[3]);   // q=128,129
                }
            }
        }
        __builtin_amdgcn_s_setprio(0);
        // S^T visible to all waves; prefetch stays in flight (no vmcnt drain)
        asm volatile("s_waitcnt lgkmcnt(0)\n\ts_barrier" ::: "memory");

        // conv via banded MFMA -> p=exp2 -> pack -> P (aliased LDS)
        __builtin_amdgcn_s_setprio(1);
        #pragma unroll
        for (int ct = 0; ct < 4; ++ct) {
            #pragma unroll
            for (int m = 0; m < 2; ++m) {
                bf16x8 saf = *(const bf16x8*)(st2b + (ct * 16 + arow) * 304 +
                                              w * 64 + m * 32 + kgrp * 16);
                f32x4 zacc = {0.f, 0.f, 0.f, 0.f};
                zacc = __builtin_amdgcn_mfma_f32_16x16x32_bf16(saf, bandf, zacc, 0, 0, 0);
                float p0 = exp2f(zacc[0]), p1 = exp2f(zacc[1]);
                float p2 = exp2f(zacc[2]), p3 = exp2f(zacc[3]);
                lp[m] += (p0 + p1) + (p2 + p3);
                uint2 uu;
                uu.x = cvtpk(p0, p1);
                uu.y = cvtpk(p2, p3);
                *(uint2*)(pbase + (plrow0 + m * 16) * 128 +
                          (((2 * ct + (kgrp >> 1)) ^ (arow & 7)) << 4) +
                          ((kgrp & 1) << 3)) = uu;
            }
        }
        // pin P-store -> P-read program order (per-wave DS is in-order in HW)
        __builtin_amdgcn_sched_barrier(0);
        // PV (wave-local P reads; hoisted V fragments)
        #pragma unroll
        for (int m = 0; m < 2; ++m) {
            const char* prow = pbase + (plrow0 + m * 16) * 128;
            bf16x8 pf0 = *(const bf16x8*)(prow + ((kgrp ^ (arow & 7)) << 4));
            bf16x8 pf1 = *(const bf16x8*)(prow + (((4 + kgrp) ^ (arow & 7)) << 4));
            #pragma unroll
            for (int dt = 0; dt < 4; ++dt) {
                oacc[m][dt] = __builtin_amdgcn_mfma_f32_16x16x32_bf16(
                    pf0, vf[dt][0], oacc[m][dt], 0, 0, 0);
                oacc[m][dt] = __builtin_amdgcn_mfma_f32_16x16x32_bf16(
                    pf1, vf[dt][1], oacc[m][dt], 0, 0, 0);
            }
        }
        __builtin_amdgcn_s_setprio(0);
    }

    // finalize row sums (deferred): reduce across the 4 kgrp lane-groups
    #pragma unroll
    for (int m = 0; m < 2; ++m) {
        float s = lp[m];
        s += __shfl_xor(s, 16);
        s += __shfl_xor(s, 32);
        if (kgrp == 0) row_l[w * 32 + m * 16 + arow] = s;
    }
    __syncthreads();
    #pragma unroll
    for (int m = 0; m < 2; ++m) {
        float inv[4];
        #pragma unroll
        for (int i = 0; i < 4; ++i)
            inv[i] = 1.f / row_l[w * 32 + m * 16 + kgrp * 4 + i];
        #pragma unroll
        for (int dt = 0; dt < 4; ++dt) {
            #pragma unroll
            for (int i = 0; i < 4; ++i) {
                size_t t = (size_t)region * 1024 + i0 + w * 32 + m * 16 + kgrp * 4 + i;
                ao[t * 512 + head * 64 + dt * 16 + arow] = f2bf(oacc[m][dt][i] * inv[i]);
            }
        }
    }
}

// ---------------- Kernel 3: proj GEMM (bf16 MFMA, fp32 out, un-permute) -------------
__global__ __launch_bounds__(256) void proj_kernel(
    const unsigned short* __restrict__ ab, const unsigned short* __restrict__ wb,
    const float* __restrict__ bias, float* __restrict__ out)
{
    __shared__ __align__(16) unsigned short As[128 * 64];
    __shared__ __align__(16) unsigned short Bs[128 * 64];
    const int c0t = blockIdx.x * 128;
    const int t0 = blockIdx.y * 128;
    const int tid = threadIdx.x;
    const int lane = tid & 63, w = tid >> 6;
    const int arow = lane & 15, kgrp = lane >> 4;
    const int wr = w >> 1, wc = w & 1;

    f32x4 acc[4][4];
    #pragma unroll
    for (int m = 0; m < 4; ++m)
        #pragma unroll
        for (int n = 0; n < 4; ++n) {
            f32x4 z = {0.f, 0.f, 0.f, 0.f};
            acc[m][n] = z;
        }

    for (int k0 = 0; k0 < 512; k0 += 64) {
        __syncthreads();
        #pragma unroll
        for (int it = 0; it < 4; ++it) {
            int slot = it * 256 + tid;
            int row = slot >> 3, phys = slot & 7;
            int c8 = phys ^ (row & 7);
            gload16(ab + (size_t)(t0 + row) * 512 + k0 + c8 * 8,
                    &As[(it * 256 + (w << 6)) * 8]);
            gload16(wb + (size_t)(c0t + row) * 512 + k0 + c8 * 8,
                    &Bs[(it * 256 + (w << 6)) * 8]);
        }
        __syncthreads();

        bf16x8 af[4][2], bfr[4][2];
        #pragma unroll
        for (int m = 0; m < 4; ++m) {
            int r = wr * 64 + m * 16 + arow;
            af[m][0] = *(const bf16x8*)&As[r * 64 + ((kgrp ^ (r & 7)) * 8)];
            af[m][1] = *(const bf16x8*)&As[r * 64 + (((4 + kgrp) ^ (r & 7)) * 8)];
        }
        #pragma unroll
        for (int n = 0; n < 4; ++n) {
            int r = wc * 64 + n * 16 + arow;
            bfr[n][0] = *(const bf16x8*)&Bs[r * 64 + ((kgrp ^ (r & 7)) * 8)];
            bfr[n][1] = *(const bf16x8*)&Bs[r * 64 + (((4 + kgrp) ^ (r & 7)) * 8)];
        }
        #pragma unroll
        for (int m = 0; m < 4; ++m)
            #pragma unroll
            for (int n = 0; n < 4; ++n) {
                acc[m][n] = __builtin_amdgcn_mfma_f32_16x16x32_bf16(
                    af[m][0], bfr[n][0], acc[m][n], 0, 0, 0);
                acc[m][n] = __builtin_amdgcn_mfma_f32_16x16x32_bf16(
                    af[m][1], bfr[n][1], acc[m][n], 0, 0, 0);
            }
    }

    #pragma unroll
    for (int n = 0; n < 4; ++n) {
        int cg = c0t + wc * 64 + n * 16 + arow;
        float bi = bias[cg];
        #pragma unroll
        for (int m = 0; m < 4; ++m) {
            int tb = t0 + wr * 64 + m * 16 + kgrp * 4;
            int l0 = l_from_rn(tb >> 10, tb & 1023);
            float* p = out + (size_t)l0 * 512 + cg;
            #pragma unroll
            for (int i = 0; i < 4; ++i)
                p[(size_t)i * 512] = acc[m][n][i] + bi;
        }
    }
}

extern "C" void kernel_launch(void* const* d_in, const int* in_sizes, int n_in,
                              void* d_out, int out_size, void* d_ws, size_t ws_size,
                              hipStream_t stream) {
    const float* x      = (const float*)d_in[0];
    const float* qkv_w  = (const float*)d_in[1];
    const float* qkv_b  = (const float*)d_in[2];
    const float* proj_w = (const float*)d_in[3];
    const float* proj_b = (const float*)d_in[4];
    const float* epeg_w = (const float*)d_in[5];
    const float* epeg_b = (const float*)d_in[6];
    float* out = (float*)d_out;

    const size_t NTOK = (size_t)16384 * 512;
    unsigned short* xb    = (unsigned short*)d_ws;
    unsigned short* wqkv  = xb + NTOK;
    unsigned short* wproj = wqkv + (size_t)1536 * 512;
    unsigned short* qb    = wproj + (size_t)512 * 512;
    unsigned short* kb    = qb + NTOK;
    unsigned short* vtb   = kb + NTOK;
    unsigned short* ao    = vtb + NTOK;

    cast_x_kernel<<<4096, 256, 0, stream>>>(x, xb);
    cast_w_kernel<<<384, 256, 0, stream>>>(qkv_w, wqkv);
    cast_w_kernel<<<128, 256, 0, stream>>>(proj_w, wproj);
    {
        dim3 grid(12, 128);
        qkv_kernel<<<grid, 256, 0, stream>>>(xb, wqkv, qkv_b, qb, kb, vtb);
    }
    attn_kernel<<<1024, 256, 0, stream>>>(qb, kb, vtb, epeg_w, epeg_b, ao);
    {
        dim3 grid(4, 128);
        proj_kernel<<<grid, 256, 0, stream>>>(ao, wproj, proj_b, out);
    }
}

// Round 12
// 146.965 us; speedup vs baseline: 1.1323x; 1.1323x over previous
//
#include <hip/hip_runtime.h>

// RegionAttention: bf16 MFMA everywhere.
// R12: EPEG conv FOLDED INTO Q (conv is linear in S, S linear in Q):
//   Qt = q_scaled[r] + sum_t w[t]*q_scaled[r+t-2]  (zero outside region)
// -> attention is a plain no-max flash loop: S=mfma(K,Qt); p=exp2(acc);
//    P->LDS (aliases retired K/V tile); PV. No ST2, no conv/halo MFMA.
// q is PRE-SCALED by 0.125*log2(e); epeg_b cancels in softmax.

using bf16x8 = __attribute__((ext_vector_type(8))) short;
using f32x4  = __attribute__((ext_vector_type(4))) float;

__device__ __forceinline__ unsigned short f2bf(float f) {
    unsigned u = __float_as_uint(f);
    u += 0x7fff + ((u >> 16) & 1);
    return (unsigned short)(u >> 16);
}
__device__ __forceinline__ float bf2f(unsigned short s) {
    return __uint_as_float(((unsigned)s) << 16);
}
__device__ __forceinline__ unsigned cvtpk(float lo, float hi) {
    unsigned r;
    asm("v_cvt_pk_bf16_f32 %0, %1, %2" : "=v"(r) : "v"(lo), "v"(hi));
    return r;
}
__device__ __forceinline__ void gload16(const void* g, void* l) {
    __builtin_amdgcn_global_load_lds(
        (const __attribute__((address_space(1))) void*)g,
        (__attribute__((address_space(3))) void*)l, 16, 0, 0);
}
__device__ __forceinline__ int l_from_rn(int region, int n) {
    int gi = region >> 2, gj = region & 3;
    int a = n >> 5, b = n & 31;
    return ((gi * 32 + a) << 7) + (gj << 5) + b;
}

// ---------------- cast kernels ----------------
__global__ __launch_bounds__(256) void cast_x_kernel(
    const float* __restrict__ x, unsigned short* __restrict__ xb)
{
    int tid = threadIdx.x;
    int t = blockIdx.x * 4 + (tid >> 6);
    int c8 = tid & 63;
    int l = l_from_rn(t >> 10, t & 1023);
    const float* src = x + (size_t)l * 512 + c8 * 8;
    float4 a = *(const float4*)src;
    float4 b = *(const float4*)(src + 4);
    bf16x8 o;
    o[0] = (short)f2bf(a.x); o[1] = (short)f2bf(a.y);
    o[2] = (short)f2bf(a.z); o[3] = (short)f2bf(a.w);
    o[4] = (short)f2bf(b.x); o[5] = (short)f2bf(b.y);
    o[6] = (short)f2bf(b.z); o[7] = (short)f2bf(b.w);
    *(bf16x8*)(xb + (size_t)t * 512 + c8 * 8) = o;
}

__global__ __launch_bounds__(256) void cast_w_kernel(
    const float* __restrict__ w, unsigned short* __restrict__ wb)
{
    int g = blockIdx.x * 256 + threadIdx.x;
    const float* src = w + (size_t)g * 8;
    float4 a = *(const float4*)src;
    float4 b = *(const float4*)(src + 4);
    bf16x8 o;
    o[0] = (short)f2bf(a.x); o[1] = (short)f2bf(a.y);
    o[2] = (short)f2bf(a.z); o[3] = (short)f2bf(a.w);
    o[4] = (short)f2bf(b.x); o[5] = (short)f2bf(b.y);
    o[6] = (short)f2bf(b.z); o[7] = (short)f2bf(b.w);
    *(bf16x8*)(wb + (size_t)g * 8) = o;
}

// ---------------- Kernel 1: QKV GEMM (bf16 MFMA) ----------------
__global__ __launch_bounds__(256) void qkv_kernel(
    const unsigned short* __restrict__ xb, const unsigned short* __restrict__ wb,
    const float* __restrict__ bias, unsigned short* __restrict__ qo,
    unsigned short* __restrict__ ko, unsigned short* __restrict__ vto)
{
    __shared__ __align__(16) unsigned short As[128 * 64];
    __shared__ __align__(16) unsigned short Bs[128 * 64];
    const int c0t = blockIdx.x * 128;
    const int t0 = blockIdx.y * 128;
    const int tid = threadIdx.x;
    const int lane = tid & 63, w = tid >> 6;
    const int arow = lane & 15, kgrp = lane >> 4;
    const int wr = w >> 1, wc = w & 1;

    f32x4 acc[4][4];
    #pragma unroll
    for (int m = 0; m < 4; ++m)
        #pragma unroll
        for (int n = 0; n < 4; ++n) {
            f32x4 z = {0.f, 0.f, 0.f, 0.f};
            acc[m][n] = z;
        }

    for (int k0 = 0; k0 < 512; k0 += 64) {
        __syncthreads();
        #pragma unroll
        for (int it = 0; it < 4; ++it) {
            int slot = it * 256 + tid;
            int row = slot >> 3, phys = slot & 7;
            int c8 = phys ^ (row & 7);
            gload16(xb + (size_t)(t0 + row) * 512 + k0 + c8 * 8,
                    &As[(it * 256 + (w << 6)) * 8]);
            gload16(wb + (size_t)(c0t + row) * 512 + k0 + c8 * 8,
                    &Bs[(it * 256 + (w << 6)) * 8]);
        }
        __syncthreads();

        bf16x8 af[4][2], bfr[4][2];
        #pragma unroll
        for (int m = 0; m < 4; ++m) {
            int r = wr * 64 + m * 16 + arow;
            af[m][0] = *(const bf16x8*)&As[r * 64 + ((kgrp ^ (r & 7)) * 8)];
            af[m][1] = *(const bf16x8*)&As[r * 64 + (((4 + kgrp) ^ (r & 7)) * 8)];
        }
        #pragma unroll
        for (int n = 0; n < 4; ++n) {
            int r = wc * 64 + n * 16 + arow;
            bfr[n][0] = *(const bf16x8*)&Bs[r * 64 + ((kgrp ^ (r & 7)) * 8)];
            bfr[n][1] = *(const bf16x8*)&Bs[r * 64 + (((4 + kgrp) ^ (r & 7)) * 8)];
        }
        #pragma unroll
        for (int m = 0; m < 4; ++m)
            #pragma unroll
            for (int n = 0; n < 4; ++n) {
                acc[m][n] = __builtin_amdgcn_mfma_f32_16x16x32_bf16(
                    af[m][0], bfr[n][0], acc[m][n], 0, 0, 0);
                acc[m][n] = __builtin_amdgcn_mfma_f32_16x16x32_bf16(
                    af[m][1], bfr[n][1], acc[m][n], 0, 0, 0);
            }
    }

    const int s = c0t >> 9;
    const int region = t0 >> 10;
    // q pre-scale: 0.125 (attn scale) * log2(e) (exp2-domain softmax)
    const float qs = (s == 0) ? 0.18033688f : 1.0f;
    #pragma unroll
    for (int n = 0; n < 4; ++n) {
        int cg = c0t + wc * 64 + n * 16 + arow;
        float bi = bias[cg];
        int h = (cg >> 6) & 7, d = cg & 63;
        if (s < 2) {
            unsigned short* dst = (s == 0) ? qo : ko;
            #pragma unroll
            for (int m = 0; m < 4; ++m) {
                int tb = t0 + wr * 64 + m * 16 + kgrp * 4;
                unsigned short* p =
                    dst + ((size_t)(region * 8 + h) * 1024 + (tb & 1023)) * 64 + d;
                #pragma unroll
                for (int i = 0; i < 4; ++i)
                    p[(size_t)i * 64] = f2bf((acc[m][n][i] + bi) * qs);
            }
        } else {
            #pragma unroll
            for (int m = 0; m < 4; ++m) {
                int tb = t0 + wr * 64 + m * 16 + kgrp * 4;
                ushort4 pk;
                pk.x = f2bf(acc[m][n][0] + bi);
                pk.y = f2bf(acc[m][n][1] + bi);
                pk.z = f2bf(acc[m][n][2] + bi);
                pk.w = f2bf(acc[m][n][3] + bi);
                *(ushort4*)(vto + (size_t)(region * 8 + h) * 65536 +
                            (size_t)d * 1024 + (tb & 1023)) = pk;
            }
        }
    }
}

// ---------------- Kernel 2: attention with conv folded into Q ----------------
__global__ __launch_bounds__(256) void attn_kernel(
    const unsigned short* __restrict__ qg, const unsigned short* __restrict__ kg,
    const unsigned short* __restrict__ vtg, const float* __restrict__ epw,
    const float* __restrict__ epb, unsigned short* __restrict__ ao)
{
    // XCD swizzle: 1024 blocks; all 8 i-blocks of one rh on one XCD
    const int bid = blockIdx.x;
    const int wid = (bid & 7) * 128 + (bid >> 3);
    const int rb = wid & 7;          // i-block (128 q rows)
    const int rh = wid >> 3;         // region*8 + head
    const int head = rh & 7, region = rh >> 3;
    const unsigned short* qb = qg + (size_t)rh * 65536;
    const unsigned short* kb = kg + (size_t)rh * 65536;
    const unsigned short* vb = vtg + (size_t)rh * 65536;
    const int i0 = rb * 128;
    const int tid = threadIdx.x;
    const int lane = tid & 63, w = tid >> 6;
    const int arow = lane & 15, kgrp = lane >> 4;

    __shared__ __align__(16) unsigned short Ks[2][4096];
    __shared__ __align__(16) unsigned short VTs[2][4096];
    __shared__ float row_l[128];
    // P (128 q rows x 128 B) aliases the RETIRED current K/V buffers after the
    // mid barrier: rows 0..63 -> Ks[cur], rows 64..127 -> VTs[cur].

    // conv taps (center gets +1 identity); q already carries 0.125*log2e
    float c_[5];
    #pragma unroll
    for (int t = 0; t < 5; ++t) c_[t] = epw[head * 5 + t];
    c_[2] += 1.0f;

    // Qt fragments: Qt[r] = sum_t c_[t] * q[r+t-2] (rows outside [0,1024)=0)
    bf16x8 qtf[2][2];
    #pragma unroll
    for (int m = 0; m < 2; ++m) {
        int gr = i0 + w * 32 + m * 16 + arow;
        float av[8], bv[8];
        #pragma unroll
        for (int e = 0; e < 8; ++e) { av[e] = 0.f; bv[e] = 0.f; }
        #pragma unroll
        for (int t = 0; t < 5; ++t) {
            int r = gr + t - 2;
            if (r >= 0 && r < 1024) {
                const unsigned short* p = qb + (size_t)r * 64 + kgrp * 8;
                bf16x8 a = *(const bf16x8*)p;
                bf16x8 b = *(const bf16x8*)(p + 32);
                float ct = c_[t];
                #pragma unroll
                for (int e = 0; e < 8; ++e) {
                    av[e] += ct * bf2f((unsigned short)a[e]);
                    bv[e] += ct * bf2f((unsigned short)b[e]);
                }
            }
        }
        union { unsigned u[4]; bf16x8 v; } pa, pb;
        #pragma unroll
        for (int e2 = 0; e2 < 4; ++e2) {
            pa.u[e2] = cvtpk(av[e2 * 2], av[e2 * 2 + 1]);
            pb.u[e2] = cvtpk(bv[e2 * 2], bv[e2 * 2 + 1]);
        }
        qtf[m][0] = pa.v;
        qtf[m][1] = pb.v;
    }

    f32x4 oacc[2][4];
    #pragma unroll
    for (int m = 0; m < 2; ++m)
        #pragma unroll
        for (int dt = 0; dt < 4; ++dt) {
            f32x4 z = {0.f, 0.f, 0.f, 0.f};
            oacc[m][dt] = z;
        }
    float lp[2] = {0.f, 0.f};

    auto stage = [&](int jt, int buf) {
        const int j0 = jt * 64;
        #pragma unroll
        for (int it = 0; it < 2; ++it) {
            int q_ = (it * 4 + w) * 64 + lane;
            int row = q_ >> 3, phys = q_ & 7, c8 = phys ^ (row & 7);
            gload16(kb + (size_t)(j0 + row) * 64 + c8 * 8,
                    &Ks[buf][(it * 4 + w) * 512]);
            gload16(vb + (size_t)row * 1024 + j0 + c8 * 8,
                    &VTs[buf][(it * 4 + w) * 512]);
        }
    };

    stage(0, 0);

    for (int jt = 0; jt < 16; ++jt) {
        const int cur = jt & 1;
        __syncthreads();   // staged tile landed (vmcnt drained); P reads done
        if (jt < 15) stage(jt + 1, cur ^ 1);

        const unsigned short* Kc = &Ks[cur][0];
        const unsigned short* Vc = &VTs[cur][0];
        char* const pbase = (w < 2) ? (char*)&Ks[cur][0] : (char*)&VTs[cur][0];
        const int plrow0 = (w & 1) * 32 + arow;

        // hoisted V fragments (retire VTs[cur] before the mid barrier)
        bf16x8 vf[4][2];
        #pragma unroll
        for (int dt = 0; dt < 4; ++dt) {
            int drow = dt * 16 + arow;
            vf[dt][0] = *(const bf16x8*)&Vc[drow * 64 + ((kgrp ^ (drow & 7)) * 8)];
            vf[dt][1] = *(const bf16x8*)&Vc[drow * 64 + (((4 + kgrp) ^ (drow & 7)) * 8)];
        }

        // S~ = mfma(K, Qt): lane holds p(q = w*32+m*16+arow, j = ct*16+kgrp*4+i)
        // -> exp2 on the accumulator, pack to bf16, hold in regs till barrier
        uint2 pu[4][2];
        __builtin_amdgcn_s_setprio(1);
        #pragma unroll
        for (int ct = 0; ct < 4; ++ct) {
            int krow = ct * 16 + arow;
            bf16x8 kf0 = *(const bf16x8*)&Kc[krow * 64 + ((kgrp ^ (krow & 7)) * 8)];
            bf16x8 kf1 = *(const bf16x8*)&Kc[krow * 64 + (((4 + kgrp) ^ (krow & 7)) * 8)];
            #pragma unroll
            for (int m = 0; m < 2; ++m) {
                f32x4 sacc = {0.f, 0.f, 0.f, 0.f};
                sacc = __builtin_amdgcn_mfma_f32_16x16x32_bf16(kf0, qtf[m][0], sacc, 0, 0, 0);
                sacc = __builtin_amdgcn_mfma_f32_16x16x32_bf16(kf1, qtf[m][1], sacc, 0, 0, 0);
                float p0 = exp2f(sacc[0]), p1 = exp2f(sacc[1]);
                float p2 = exp2f(sacc[2]), p3 = exp2f(sacc[3]);
                lp[m] += (p0 + p1) + (p2 + p3);
                pu[ct][m].x = cvtpk(p0, p1);
                pu[ct][m].y = cvtpk(p2, p3);
            }
        }
        __builtin_amdgcn_s_setprio(0);
        // all waves' K/V reads complete -> safe to overwrite with P;
        // prefetch (vmcnt) stays in flight
        asm volatile("s_waitcnt lgkmcnt(0)\n\ts_barrier" ::: "memory");

        // P -> aliased LDS (wave-local rows)
        #pragma unroll
        for (int ct = 0; ct < 4; ++ct)
            #pragma unroll
            for (int m = 0; m < 2; ++m)
                *(uint2*)(pbase + (plrow0 + m * 16) * 128 +
                          (((2 * ct + (kgrp >> 1)) ^ (arow & 7)) << 4) +
                          ((kgrp & 1) << 3)) = pu[ct][m];
        // pin P-store -> P-read program order (per-wave DS is in-order in HW)
        __builtin_amdgcn_sched_barrier(0);
        // PV (wave-local P reads; hoisted V fragments)
        __builtin_amdgcn_s_setprio(1);
        #pragma unroll
        for (int m = 0; m < 2; ++m) {
            const char* prow = pbase + (plrow0 + m * 16) * 128;
            bf16x8 pf0 = *(const bf16x8*)(prow + ((kgrp ^ (arow & 7)) << 4));
            bf16x8 pf1 = *(const bf16x8*)(prow + (((4 + kgrp) ^ (arow & 7)) << 4));
            #pragma unroll
            for (int dt = 0; dt < 4; ++dt) {
                oacc[m][dt] = __builtin_amdgcn_mfma_f32_16x16x32_bf16(
                    pf0, vf[dt][0], oacc[m][dt], 0, 0, 0);
                oacc[m][dt] = __builtin_amdgcn_mfma_f32_16x16x32_bf16(
                    pf1, vf[dt][1], oacc[m][dt], 0, 0, 0);
            }
        }
        __builtin_amdgcn_s_setprio(0);
    }

    // finalize row sums: reduce across the 4 kgrp lane-groups
    #pragma unroll
    for (int m = 0; m < 2; ++m) {
        float s = lp[m];
        s += __shfl_xor(s, 16);
        s += __shfl_xor(s, 32);
        if (kgrp == 0) row_l[w * 32 + m * 16 + arow] = s;
    }
    __syncthreads();
    #pragma unroll
    for (int m = 0; m < 2; ++m) {
        float inv[4];
        #pragma unroll
        for (int i = 0; i < 4; ++i)
            inv[i] = 1.f / row_l[w * 32 + m * 16 + kgrp * 4 + i];
        #pragma unroll
        for (int dt = 0; dt < 4; ++dt) {
            #pragma unroll
            for (int i = 0; i < 4; ++i) {
                size_t t = (size_t)region * 1024 + i0 + w * 32 + m * 16 + kgrp * 4 + i;
                ao[t * 512 + head * 64 + dt * 16 + arow] = f2bf(oacc[m][dt][i] * inv[i]);
            }
        }
    }
}

// ---------------- Kernel 3: proj GEMM (bf16 MFMA, fp32 out, un-permute) -------------
__global__ __launch_bounds__(256) void proj_kernel(
    const unsigned short* __restrict__ ab, const unsigned short* __restrict__ wb,
    const float* __restrict__ bias, float* __restrict__ out)
{
    __shared__ __align__(16) unsigned short As[128 * 64];
    __shared__ __align__(16) unsigned short Bs[128 * 64];
    const int c0t = blockIdx.x * 128;
    const int t0 = blockIdx.y * 128;
    const int tid = threadIdx.x;
    const int lane = tid & 63, w = tid >> 6;
    const int arow = lane & 15, kgrp = lane >> 4;
    const int wr = w >> 1, wc = w & 1;

    f32x4 acc[4][4];
    #pragma unroll
    for (int m = 0; m < 4; ++m)
        #pragma unroll
        for (int n = 0; n < 4; ++n) {
            f32x4 z = {0.f, 0.f, 0.f, 0.f};
            acc[m][n] = z;
        }

    for (int k0 = 0; k0 < 512; k0 += 64) {
        __syncthreads();
        #pragma unroll
        for (int it = 0; it < 4; ++it) {
            int slot = it * 256 + tid;
            int row = slot >> 3, phys = slot & 7;
            int c8 = phys ^ (row & 7);
            gload16(ab + (size_t)(t0 + row) * 512 + k0 + c8 * 8,
                    &As[(it * 256 + (w << 6)) * 8]);
            gload16(wb + (size_t)(c0t + row) * 512 + k0 + c8 * 8,
                    &Bs[(it * 256 + (w << 6)) * 8]);
        }
        __syncthreads();

        bf16x8 af[4][2], bfr[4][2];
        #pragma unroll
        for (int m = 0; m < 4; ++m) {
            int r = wr * 64 + m * 16 + arow;
            af[m][0] = *(const bf16x8*)&As[r * 64 + ((kgrp ^ (r & 7)) * 8)];
            af[m][1] = *(const bf16x8*)&As[r * 64 + (((4 + kgrp) ^ (r & 7)) * 8)];
        }
        #pragma unroll
        for (int n = 0; n < 4; ++n) {
            int r = wc * 64 + n * 16 + arow;
            bfr[n][0] = *(const bf16x8*)&Bs[r * 64 + ((kgrp ^ (r & 7)) * 8)];
            bfr[n][1] = *(const bf16x8*)&Bs[r * 64 + (((4 + kgrp) ^ (r & 7)) * 8)];
        }
        #pragma unroll
        for (int m = 0; m < 4; ++m)
            #pragma unroll
            for (int n = 0; n < 4; ++n) {
                acc[m][n] = __builtin_amdgcn_mfma_f32_16x16x32_bf16(
                    af[m][0], bfr[n][0], acc[m][n], 0, 0, 0);
                acc[m][n] = __builtin_amdgcn_mfma_f32_16x16x32_bf16(
                    af[m][1], bfr[n][1], acc[m][n], 0, 0, 0);
            }
    }

    #pragma unroll
    for (int n = 0; n < 4; ++n) {
        int cg = c0t + wc * 64 + n * 16 + arow;
        float bi = bias[cg];
        #pragma unroll
        for (int m = 0; m < 4; ++m) {
            int tb = t0 + wr * 64 + m * 16 + kgrp * 4;
            int l0 = l_from_rn(tb >> 10, tb & 1023);
            float* p = out + (size_t)l0 * 512 + cg;
            #pragma unroll
            for (int i = 0; i < 4; ++i)
                p[(size_t)i * 512] = acc[m][n][i] + bi;
        }
    }
}

extern "C" void kernel_launch(void* const* d_in, const int* in_sizes, int n_in,
                              void* d_out, int out_size, void* d_ws, size_t ws_size,
                              hipStream_t stream) {
    const float* x      = (const float*)d_in[0];
    const float* qkv_w  = (const float*)d_in[1];
    const float* qkv_b  = (const float*)d_in[2];
    const float* proj_w = (const float*)d_in[3];
    const float* proj_b = (const float*)d_in[4];
    const float* epeg_w = (const float*)d_in[5];
    const float* epeg_b = (const float*)d_in[6];
    float* out = (float*)d_out;

    const size_t NTOK = (size_t)16384 * 512;
    unsigned short* xb    = (unsigned short*)d_ws;
    unsigned short* wqkv  = xb + NTOK;
    unsigned short* wproj = wqkv + (size_t)1536 * 512;
    unsigned short* qb    = wproj + (size_t)512 * 512;
    unsigned short* kb    = qb + NTOK;
    unsigned short* vtb   = kb + NTOK;
    unsigned short* ao    = vtb + NTOK;

    cast_x_kernel<<<4096, 256, 0, stream>>>(x, xb);
    cast_w_kernel<<<384, 256, 0, stream>>>(qkv_w, wqkv);
    cast_w_kernel<<<128, 256, 0, stream>>>(proj_w, wproj);
    {
        dim3 grid(12, 128);
        qkv_kernel<<<grid, 256, 0, stream>>>(xb, wqkv, qkv_b, qb, kb, vtb);
    }
    attn_kernel<<<1024, 256, 0, stream>>>(qb, kb, vtb, epeg_w, epeg_b, ao);
    {
        dim3 grid(4, 128);
        proj_kernel<<<grid, 256, 0, stream>>>(ao, wproj, proj_b, out);
    }
}